// Round 2
// baseline (325.002 us; speedup 1.0000x reference)
//
#include <hip/hip_runtime.h>

#define WAVE 64
#define CAP 64  // per-node bucket capacity; P(deg>=64 | Poisson(16)) ~ 1e-19

typedef __bf16 v8bf __attribute__((ext_vector_type(8)));
typedef __bf16 v4bf __attribute__((ext_vector_type(4)));
typedef __bf16 v2bf __attribute__((ext_vector_type(2)));
typedef float f32x4 __attribute__((ext_vector_type(4)));

// async global->LDS 16B/lane: lds dest is WAVE-UNIFORM base (+lane*16 by HW);
// global src is per-lane.
__device__ __forceinline__ void async16(void* lds, const void* g) {
    __builtin_amdgcn_global_load_lds((const __attribute__((address_space(1))) void*)g,
                                     (__attribute__((address_space(3))) void*)lds, 16, 0, 0);
}

// ---------------- prep: wconv(W1) + wconv(W2) only ----------------
// blocks [0,256): W1 transpose/split; [256,288): W2
__global__ __launch_bounds__(256) void prep_kernel(const float* __restrict__ W1,
                                                   const float* __restrict__ W2,
                                                   __bf16* __restrict__ Wt1hi,
                                                   __bf16* __restrict__ Wt1lo,
                                                   __bf16* __restrict__ Wt2hi,
                                                   __bf16* __restrict__ Wt2lo) {
    int b = blockIdx.x;
    int tid = threadIdx.x;
    if (b < 256) {  // W1: K=512, N=128
        int idx = b * 256 + tid;
        int k = idx >> 7, n = idx & 127;
        float v = W1[idx];
        __bf16 h = (__bf16)v;
        Wt1hi[n * 512 + k] = h;
        Wt1lo[n * 512 + k] = (__bf16)(v - (float)h);
    } else {  // W2: K=128, N=64
        int idx = (b - 256) * 256 + tid;
        int k = idx >> 6, n = idx & 63;
        float v = W2[idx];
        __bf16 h = (__bf16)v;
        Wt2hi[n * 128 + k] = h;
        Wt2lo[n * 128 + k] = (__bf16)(v - (float)h);
    }
}

// ---------------- fused: async-LDS split-bf16 MFMA GEMM + bucket fill ----------------
// blocks [0,NG): gemm tile; [NG, NG+NF): fill (independent, co-scheduled).
// GEMM: C[r,c] = sum_k A[r,k] B[k,c] (NO dinv scaling — applied in gather).
// A staged fp32 via global_load_lds (swizzled source, linear LDS); converted to
// split-bf16 at fragment read. B staged as split-bf16 hi/lo. Double-buffered,
// ONE barrier per K-step (T3-minimum 2-phase template).
// Fill: p = atomicAdd(cursor[dst]); srcs[dst*CAP+p] = src. cursor becomes degree.
template <int NC, int KK, bool OBF16, bool FILL>
__global__ __launch_bounds__(256, 2) void gemm_fill_kernel(
    const float* __restrict__ A, const __bf16* __restrict__ Bhi,
    const __bf16* __restrict__ Blo, void* __restrict__ Cout, int M, int NG,
    const int* __restrict__ ei, int E, int* __restrict__ cursor,
    int* __restrict__ srcs) {
    constexpr int BK = 32;
    constexpr int NT = NC / 16;
    constexpr int NIT = KK / BK;
    constexpr int CHB = NC / 16;  // 1KB chunks per B half-tile

    // A: [2 buf][128 rows][32 k] fp32, linear (gload_lds), source-swizzled:
    //    phys 16B-slot p of row r holds logical slot p ^ (r&7).
    // B: [2 buf][hi/lo][NC rows][32 k] bf16, phys slot p = logical ^ ((r>>1)&3).
    __shared__ float sA[2][128 * 32];
    __shared__ __bf16 sB[2][2][NC * 32];

    const int tid = threadIdx.x;

    if (FILL && blockIdx.x >= NG) {  // ---- fill path: 2 edges per thread ----
        int bb = (blockIdx.x - NG) * 512;
#pragma unroll
        for (int j = 0; j < 2; ++j) {
            int e = bb + tid + j * 256;
            if (e < E) {
                int dst = ei[E + e];
                int p = atomicAdd(&cursor[dst], 1);
                if (p < CAP) srcs[(size_t)dst * CAP + p] = ei[e];
            }
        }
        return;
    }

    const int lane = tid & 63;
    const int wv = tid >> 6;
    const int ln15 = lane & 15;
    const int quad = lane >> 4;
    const int rowBase = blockIdx.x * 128;

    // ---- staging lambdas (all lanes active, uniform control flow) ----
    auto stageA = [&](int buf, int k0) {
#pragma unroll
        for (int i = 0; i < 4; ++i) {
            int c = wv + i * 4;              // chunk 0..15 (1KB = 8 rows x 128B)
            int row = c * 8 + (lane >> 3);   // row within tile
            int p = lane & 7;                // phys 16B slot
            int grow = rowBase + row;
            if (grow > M - 1) grow = M - 1;  // clamp (garbage rows unused)
            int gcol = k0 + ((p ^ (row & 7)) << 2);  // logical slot -> 4 floats
            async16(&sA[buf][c * 256], A + (size_t)grow * KK + gcol);
        }
    };
    auto stageB = [&](int buf, int k0) {
        for (int i = wv; i < CHB; i += 4) {  // 1KB chunk = 16 rows x 64B
            int row = i * 16 + (lane >> 2);
            int p = lane & 3;
            int gk = k0 + ((p ^ ((row >> 1) & 3)) << 3);  // logical slot -> 8 bf16
            async16(&sB[buf][0][i * 512], Bhi + (size_t)row * KK + gk);
            async16(&sB[buf][1][i * 512], Blo + (size_t)row * KK + gk);
        }
    };

    f32x4 acc[2][NT];
#pragma unroll
    for (int rt = 0; rt < 2; ++rt)
#pragma unroll
        for (int t = 0; t < NT; ++t) acc[rt][t] = (f32x4){0.f, 0.f, 0.f, 0.f};

    stageA(0, 0);
    stageB(0, 0);
    __syncthreads();  // drains vmcnt(0): buf0 ready

    int cur = 0;
    for (int it = 0; it < NIT; ++it) {
        // issue next tile's async loads first: latency hides under compute
        if (it + 1 < NIT) {
            stageA(cur ^ 1, (it + 1) * BK);
            stageB(cur ^ 1, (it + 1) * BK);
        }

        // A fragments: fp32 from LDS (swizzled), convert to split-bf16 in regs
        v8bf ah[2], al[2];
#pragma unroll
        for (int rt = 0; rt < 2; ++rt) {
            int row = wv * 32 + rt * 16 + ln15;
            int sw = row & 7;
            const float* base = &sA[cur][row * 32];
            f32x4 u = *(const f32x4*)(base + (((2 * quad) ^ sw) << 2));
            f32x4 v = *(const f32x4*)(base + (((2 * quad + 1) ^ sw) << 2));
            float f[8] = {u.x, u.y, u.z, u.w, v.x, v.y, v.z, v.w};
#pragma unroll
            for (int j = 0; j < 8; ++j) {
                __bf16 h = (__bf16)f[j];
                ah[rt][j] = h;
                al[rt][j] = (__bf16)(f[j] - (float)h);
            }
        }

#pragma unroll
        for (int t = 0; t < NT; ++t) {
            int row = t * 16 + ln15;
            int sw = (row >> 1) & 3;
            v8bf bh = *(const v8bf*)&sB[cur][0][row * 32 + ((quad ^ sw) << 3)];
            v8bf bl = *(const v8bf*)&sB[cur][1][row * 32 + ((quad ^ sw) << 3)];
#pragma unroll
            for (int rt = 0; rt < 2; ++rt) {
                acc[rt][t] = __builtin_amdgcn_mfma_f32_16x16x32_bf16(ah[rt], bh, acc[rt][t], 0, 0, 0);
                acc[rt][t] = __builtin_amdgcn_mfma_f32_16x16x32_bf16(al[rt], bh, acc[rt][t], 0, 0, 0);
                acc[rt][t] = __builtin_amdgcn_mfma_f32_16x16x32_bf16(ah[rt], bl, acc[rt][t], 0, 0, 0);
            }
        }

        __syncthreads();  // drains vmcnt(0): next buf staged AND cur reads done
        cur ^= 1;
    }

    // C/D layout: col=ln15, row=quad*4+reg
#pragma unroll
    for (int rt = 0; rt < 2; ++rt) {
#pragma unroll
        for (int r = 0; r < 4; ++r) {
            int grow = rowBase + wv * 32 + rt * 16 + quad * 4 + r;
            if (grow < M) {
#pragma unroll
                for (int t = 0; t < NT; ++t) {
                    float v = acc[rt][t][r];
                    if (OBF16)
                        ((__bf16*)Cout)[(size_t)grow * NC + t * 16 + ln15] = (__bf16)v;
                    else
                        ((float*)Cout)[(size_t)grow * NC + t * 16 + ln15] = v;
                }
            }
        }
    }
}

// ---------------- gather-aggregate, dinv on the fly ----------------
// out[n,j] = [relu]( dn*( sum_e ds_e*hs[src_e,j] + dn*hs[n,j] ) + bias[j] ),
// dn = rsqrt(deg[n]+1), ds = rsqrt(deg[src]+1); deg = counts (= cursor after fill)
template <int F, bool RELU, bool BF16OUT>
__global__ __launch_bounds__(256) void gather_agg_bf16(const __bf16* __restrict__ hs,
                                                       const int* __restrict__ counts,
                                                       const int* __restrict__ srcs,
                                                       const float* __restrict__ bias,
                                                       void* __restrict__ outp, int N) {
    int node = blockIdx.x * 4 + (int)(threadIdx.x >> 6);
    if (node >= N) return;
    int lane = threadIdx.x & 63;
    int cnt = counts[node];
    if (cnt > CAP) cnt = CAP;
    int beg = node * CAP;
    int end = beg + cnt;
    float dn = rsqrtf((float)cnt + 1.0f);

    if constexpr (F == 128) {
        int col = 2 * lane;
        float a0, a1;
        {
            v2bf s = *(const v2bf*)&hs[(size_t)node * F + col];
            a0 = dn * (float)s[0];
            a1 = dn * (float)s[1];
        }
        int e = beg;
        for (; e + 4 <= end; e += 4) {
            int s0 = srcs[e], s1 = srcs[e + 1], s2 = srcs[e + 2], s3 = srcs[e + 3];
            float d0 = rsqrtf((float)counts[s0] + 1.0f);
            float d1 = rsqrtf((float)counts[s1] + 1.0f);
            float d2 = rsqrtf((float)counts[s2] + 1.0f);
            float d3 = rsqrtf((float)counts[s3] + 1.0f);
            v2bf r0 = *(const v2bf*)&hs[(size_t)s0 * F + col];
            v2bf r1 = *(const v2bf*)&hs[(size_t)s1 * F + col];
            v2bf r2 = *(const v2bf*)&hs[(size_t)s2 * F + col];
            v2bf r3 = *(const v2bf*)&hs[(size_t)s3 * F + col];
            a0 += d0 * (float)r0[0] + d1 * (float)r1[0] + d2 * (float)r2[0] + d3 * (float)r3[0];
            a1 += d0 * (float)r0[1] + d1 * (float)r1[1] + d2 * (float)r2[1] + d3 * (float)r3[1];
        }
        for (; e < end; ++e) {
            int s0 = srcs[e];
            float d0 = rsqrtf((float)counts[s0] + 1.0f);
            v2bf r0 = *(const v2bf*)&hs[(size_t)s0 * F + col];
            a0 += d0 * (float)r0[0];
            a1 += d0 * (float)r0[1];
        }
        float2 bv = *(const float2*)&bias[col];
        float v0 = dn * a0 + bv.x;
        float v1 = dn * a1 + bv.y;
        if (RELU) {
            v0 = fmaxf(v0, 0.f);
            v1 = fmaxf(v1, 0.f);
        }
        if (BF16OUT) {
            v2bf o;
            o[0] = (__bf16)v0;
            o[1] = (__bf16)v1;
            *(v2bf*)&((__bf16*)outp)[(size_t)node * F + col] = o;
        } else {
            *(float2*)&((float*)outp)[(size_t)node * F + col] = make_float2(v0, v1);
        }
    } else {
        // F == 64: 4 quarter-waves of 16 lanes; each takes every 4th edge;
        // lane covers 4 cols (v4bf). Combine via shfl_xor(16), shfl_xor(32).
        int q = lane >> 4;
        int sl = lane & 15;
        int col = sl * 4;
        float a0 = 0.f, a1 = 0.f, a2 = 0.f, a3 = 0.f;
        if (q == 0) {
            v4bf s = *(const v4bf*)&hs[(size_t)node * F + col];
            a0 = dn * (float)s[0]; a1 = dn * (float)s[1];
            a2 = dn * (float)s[2]; a3 = dn * (float)s[3];
        }
        int e = beg + q;
        for (; e + 4 < end; e += 8) {
            int s0 = srcs[e], s1 = srcs[e + 4];
            float d0 = rsqrtf((float)counts[s0] + 1.0f);
            float d1 = rsqrtf((float)counts[s1] + 1.0f);
            v4bf r0 = *(const v4bf*)&hs[(size_t)s0 * F + col];
            v4bf r1 = *(const v4bf*)&hs[(size_t)s1 * F + col];
            a0 += d0 * (float)r0[0] + d1 * (float)r1[0];
            a1 += d0 * (float)r0[1] + d1 * (float)r1[1];
            a2 += d0 * (float)r0[2] + d1 * (float)r1[2];
            a3 += d0 * (float)r0[3] + d1 * (float)r1[3];
        }
        if (e < end) {
            int s0 = srcs[e];
            float d0 = rsqrtf((float)counts[s0] + 1.0f);
            v4bf r0 = *(const v4bf*)&hs[(size_t)s0 * F + col];
            a0 += d0 * (float)r0[0]; a1 += d0 * (float)r0[1];
            a2 += d0 * (float)r0[2]; a3 += d0 * (float)r0[3];
        }
        a0 += __shfl_xor(a0, 16); a0 += __shfl_xor(a0, 32);
        a1 += __shfl_xor(a1, 16); a1 += __shfl_xor(a1, 32);
        a2 += __shfl_xor(a2, 16); a2 += __shfl_xor(a2, 32);
        a3 += __shfl_xor(a3, 16); a3 += __shfl_xor(a3, 32);
        if (q == 0) {
            float4 bv = *(const float4*)&bias[col];
            float v0 = dn * a0 + bv.x;
            float v1 = dn * a1 + bv.y;
            float v2 = dn * a2 + bv.z;
            float v3 = dn * a3 + bv.w;
            if (RELU) {
                v0 = fmaxf(v0, 0.f); v1 = fmaxf(v1, 0.f);
                v2 = fmaxf(v2, 0.f); v3 = fmaxf(v3, 0.f);
            }
            if (BF16OUT) {
                v4bf o;
                o[0] = (__bf16)v0; o[1] = (__bf16)v1;
                o[2] = (__bf16)v2; o[3] = (__bf16)v3;
                *(v4bf*)&((__bf16*)outp)[(size_t)node * F + col] = o;
            } else {
                *(float4*)&((float*)outp)[(size_t)node * F + col] =
                    make_float4(v0, v1, v2, v3);
            }
        }
    }
}

// ---------------- decode: 4 lanes/edge, bf16 z rows (128 B) ----------------
__global__ __launch_bounds__(256) void decode_bf16_kernel(const __bf16* __restrict__ z,
                                                          const int* __restrict__ pos,
                                                          const int* __restrict__ neg, int E,
                                                          float* __restrict__ out) {
    int tid = blockIdx.x * blockDim.x + threadIdx.x;
    int g = tid >> 2;
    int l = tid & 3;
    int total = 2 * E;
    if (g >= total) return;
    int src, dst;
    if (g < E) {
        src = pos[g];
        dst = pos[E + g];
    } else {
        int e = g - E;
        src = neg[e];
        dst = neg[E + e];
    }
    const __bf16* zs = z + (size_t)src * 64 + l * 16;
    const __bf16* zd = z + (size_t)dst * 64 + l * 16;
    v8bf a0 = *(const v8bf*)zs;
    v8bf a1 = *(const v8bf*)(zs + 8);
    v8bf b0 = *(const v8bf*)zd;
    v8bf b1 = *(const v8bf*)(zd + 8);
    float p = 0.f;
#pragma unroll
    for (int j = 0; j < 8; ++j) p += (float)a0[j] * (float)b0[j] + (float)a1[j] * (float)b1[j];
    p += __shfl_xor(p, 1);
    p += __shfl_xor(p, 2);
    if (l == 0) out[g] = p;
}

extern "C" void kernel_launch(void* const* d_in, const int* in_sizes, int n_in, void* d_out,
                              int out_size, void* d_ws, size_t ws_size, hipStream_t stream) {
    const float* x = (const float*)d_in[0];
    const int* pos_ei = (const int*)d_in[1];
    const int* neg_ei = (const int*)d_in[2];
    const float* W1 = (const float*)d_in[3];
    const float* b1 = (const float*)d_in[4];
    const float* W2 = (const float*)d_in[5];
    const float* b2 = (const float*)d_in[6];
    float* out = (float*)d_out;

    const int IN = 512, HID = 128, OUT = 64;
    const int N = in_sizes[0] / IN;  // 50000
    const int E = in_sizes[1] / 2;   // 800000

    // workspace layout (4-byte units; all chunks multiples of 16 B)
    size_t nAlign = ((size_t)N + 255) & ~(size_t)255;
    float* p = (float*)d_ws;
    float* h1 = p; p += (size_t)N * HID;                 // fp32 N*128
    __bf16* hs1 = (__bf16*)p; p += (size_t)N * HID / 2;  // bf16 N*128
    __bf16* hs2 = (__bf16*)p; p += (size_t)N * OUT / 2;  // bf16 N*64
    __bf16* zbf = (__bf16*)p; p += (size_t)N * OUT / 2;  // bf16 N*64
    int* cursor = (int*)p; p += nAlign;                  // degree counts after fill
    int* srcs = (int*)p; p += (size_t)N * CAP;           // fixed buckets
    __bf16* Wt1hi = (__bf16*)p; p += (size_t)IN * HID / 2;
    __bf16* Wt1lo = (__bf16*)p; p += (size_t)IN * HID / 2;
    __bf16* Wt2hi = (__bf16*)p; p += (size_t)HID * OUT / 2;
    __bf16* Wt2lo = (__bf16*)p; p += (size_t)HID * OUT / 2;

    const int NG = (N + 127) / 128;   // 391 gemm tiles
    const int NF = (E + 511) / 512;   // 1563 fill blocks (2 edges/thread)

    // ---- prep: W transpose/split (tiny); cursor zero ----
    hipMemsetAsync(cursor, 0, (size_t)N * sizeof(int), stream);
    prep_kernel<<<288, 256, 0, stream>>>(W1, W2, Wt1hi, Wt1lo, Wt2hi, Wt2lo);

    // ---- layer 1 GEMM fused with bucket fill (both independent) ----
    gemm_fill_kernel<128, 512, true, true><<<NG + NF, 256, 0, stream>>>(
        x, Wt1hi, Wt1lo, hs1, N, NG, pos_ei, E, cursor, srcs);
    gather_agg_bf16<128, true, false>
        <<<(N + 3) / 4, 256, 0, stream>>>(hs1, cursor, srcs, b1, h1, N);

    // ---- layer 2 ----
    gemm_fill_kernel<64, 128, true, false><<<NG, 256, 0, stream>>>(
        h1, Wt2hi, Wt2lo, hs2, N, NG, nullptr, 0, nullptr, nullptr);
    gather_agg_bf16<64, false, true>
        <<<(N + 3) / 4, 256, 0, stream>>>(hs2, cursor, srcs, b2, zbf, N);

    // ---- decode ----
    decode_bf16_kernel<<<((size_t)2 * E * 4 + 255) / 256, 256, 0, stream>>>(
        zbf, pos_ei, neg_ei, E, out);
}